// Round 6
// baseline (884.926 us; speedup 1.0000x reference)
//
#include <hip/hip_runtime.h>
#include <math.h>

#define NNODES 20000
#define NEDGES 320000
#define NGRAPHS 16

// ---------------- generic tiled fp32 GEMM: C[M,N] = A[M,K] @ B[K,N] (+bias, relu) ----------------
// 64x64 tile, 256 threads, 4x4 microtile. HASEXTRA: logical column K-1 of A comes from extracol[row]
// (used to fold the [jk | gate] concat into the MLP1 GEMM without materializing a [N,257] buffer).
template<int RELU, int HASBIAS, int HASEXTRA>
__global__ __launch_bounds__(256) void gemm_kernel(
    const float* __restrict__ A, int Astride,
    const float* __restrict__ extracol,
    const float* __restrict__ B,
    const float* __restrict__ bias,
    float* __restrict__ C,
    int M, int N, int K)
{
    // As padded to 68 cols: write banks (68*kk+m)%32 = (4kk+m)%32 -> 2-way max (free);
    // row byte stride 272 = 17*16 keeps 16B alignment so fragment reads stay ds_read_b128.
    __shared__ float As[16][68];
    __shared__ float Bs[16][64];
    int t  = threadIdx.x;
    int tx = t & 15, ty = t >> 4;
    int row0 = blockIdx.x * 64;
    int col0 = blockIdx.y * 64;
    float acc[4][4] = {};
    for (int k0 = 0; k0 < K; k0 += 16) {
        #pragma unroll
        for (int i = 0; i < 4; ++i) {          // A tile: 64 rows x 16 k, stored transposed As[k][m]
            int idx = t + i * 256;
            int m = idx >> 4, kk = idx & 15;
            int gr = row0 + m, gk = k0 + kk;
            float v = 0.f;
            if (gr < M && gk < K) {
                if (HASEXTRA && gk == K - 1) v = extracol[gr];
                else                         v = A[gr * Astride + gk];
            }
            As[kk][m] = v;
        }
        #pragma unroll
        for (int i = 0; i < 4; ++i) {          // B tile: 16 k x 64 n (coalesced 256B rows)
            int idx = t + i * 256;
            int kk = idx >> 6, nn = idx & 63;
            int gk = k0 + kk, gn = col0 + nn;
            Bs[kk][nn] = (gk < K && gn < N) ? B[gk * N + gn] : 0.f;
        }
        __syncthreads();
        #pragma unroll
        for (int kk = 0; kk < 16; ++kk) {
            float a[4], b[4];
            #pragma unroll
            for (int i = 0; i < 4; ++i) a[i] = As[kk][ty * 4 + i];   // 16B-aligned -> ds_read_b128
            #pragma unroll
            for (int j = 0; j < 4; ++j) b[j] = Bs[kk][tx * 4 + j];
            #pragma unroll
            for (int i = 0; i < 4; ++i)
                #pragma unroll
                for (int j = 0; j < 4; ++j)
                    acc[i][j] = fmaf(a[i], b[j], acc[i][j]);
        }
        __syncthreads();
    }
    #pragma unroll
    for (int i = 0; i < 4; ++i) {
        int gr = row0 + ty * 4 + i;
        if (gr >= M) continue;
        #pragma unroll
        for (int j = 0; j < 4; ++j) {
            int gn = col0 + tx * 4 + j;
            if (gn >= N) continue;
            float v = acc[i][j];
            if (HASBIAS) v += bias[gn];
            if (RELU)    v = fmaxf(v, 0.f);
            C[gr * N + gn] = v;
        }
    }
}

// ---------------- per-node attention logits: als[n,h] = sum_d h[n,h,d]*a_s[h,d] ----------------
__global__ __launch_bounds__(256) void att_logits(
    const float* __restrict__ h, const float* __restrict__ a_s, const float* __restrict__ a_d,
    float* __restrict__ als, float* __restrict__ ald)
{
    int n = blockIdx.x, t = threadIdx.x;      // wave w (64 lanes) == head w
    float v  = h[n * 256 + t];
    float ps = v * a_s[t];
    float pd = v * a_d[t];
    #pragma unroll
    for (int o = 32; o; o >>= 1) { ps += __shfl_down(ps, o); pd += __shfl_down(pd, o); }
    if ((t & 63) == 0) {
        int head = t >> 6;
        als[n * 4 + head] = ps;
        ald[n * 4 + head] = pd;
    }
}

// ---------------- CSR build (dst-grouped) ----------------
__global__ void hist_kernel(const int* __restrict__ ei, int* __restrict__ cnt) {
    int e = blockIdx.x * 256 + threadIdx.x;
    if (e < NEDGES) atomicAdd(&cnt[ei[NEDGES + e]], 1);
}

// single block, 256 threads. Each thread owns a contiguous run of P counts (sequential sum),
// wave shfl-scan + 4-entry LDS combine (2 barriers total vs ~1400 in the naive chunked scan).
__global__ void scan_kernel(const int* __restrict__ cnt, int* __restrict__ off) {
    const int P = (NNODES + 255) / 256;   // 79
    int t = threadIdx.x;
    int lo = t * P, hi = lo + P; if (hi > NNODES) hi = NNODES; if (lo > NNODES) lo = NNODES;
    int s = 0;
    for (int i = lo; i < hi; ++i) s += cnt[i];
    // wave-inclusive scan of per-thread sums
    int lane = t & 63, wv = t >> 6;
    int v = s;
    #pragma unroll
    for (int o = 1; o < 64; o <<= 1) {
        int u = __shfl_up(v, o);
        if (lane >= o) v += u;
    }
    __shared__ int ws[4];
    if (lane == 63) ws[wv] = v;
    __syncthreads();
    int wbase = 0;
    for (int i = 0; i < wv; ++i) wbase += ws[i];
    int run = wbase + v - s;              // exclusive prefix for this thread's range
    for (int i = lo; i < hi; ++i) { off[i] = run; run += cnt[i]; }
    if (t == 255) off[NNODES] = run;
}

__global__ void scatter_kernel(const int* __restrict__ ei, const int* __restrict__ off,
                               int* __restrict__ cur, int* __restrict__ srcs) {
    int e = blockIdx.x * 256 + threadIdx.x;
    if (e < NEDGES) {
        int d = ei[NEDGES + e];
        int pos = off[d] + atomicAdd(&cur[d], 1);
        srcs[pos] = ei[e];
    }
}

// ---------------- GAT aggregation: one block per dst node, segment softmax + weighted sum --------
// Phase 3 chunks edges by 64: 256 threads compute the 64x4 distinct softmax weights ONCE into LDS
// (before: every thread recomputed leaky_relu+expf per edge -> 64x redundant v_exp_f32).
template<int RELU, int JKINIT>
__global__ __launch_bounds__(256) void gat_aggregate(
    const float* __restrict__ hbuf,
    const float* __restrict__ als, const float* __restrict__ ald,
    const float* __restrict__ bias,
    const int* __restrict__ off, const int* __restrict__ srcs,
    float* __restrict__ xout, float* __restrict__ jk)
{
    int n = blockIdx.x, t = threadIdx.x;
    int beg = off[n], end = off[n + 1];
    __shared__ float red[256];
    __shared__ float mh[4], sh[4];
    __shared__ float wch[64][4];   // write addr == tid (conflict-free); reads wave-uniform broadcast
    __shared__ int   sch[64];

    int h4 = t & 3;                       // thread t handles head t&3, edge (t>>2)+64k
    float aldh = ald[n * 4 + h4];
    float lmax = -INFINITY;
    for (int e = beg + (t >> 2); e < end; e += 64) {
        int s = srcs[e];
        float l = als[s * 4 + h4] + aldh;
        l = (l > 0.f) ? l : 0.2f * l;
        lmax = fmaxf(lmax, l);
    }
    red[t] = lmax;
    __syncthreads();
    #pragma unroll
    for (int st = 128; st >= 4; st >>= 1) {   // strided tree: pairs are same-head (st % 4 == 0)
        if (t < st) red[t] = fmaxf(red[t], red[t + st]);
        __syncthreads();
    }
    if (t < 4) { float m = red[t]; mh[t] = (m == -INFINITY) ? 0.f : m; }  // empty-segment guard
    __syncthreads();

    float mhh = mh[h4];
    float lsum = 0.f;
    for (int e = beg + (t >> 2); e < end; e += 64) {
        int s = srcs[e];
        float l = als[s * 4 + h4] + aldh;
        l = (l > 0.f) ? l : 0.2f * l;
        lsum += expf(l - mhh);
    }
    red[t] = lsum;
    __syncthreads();
    #pragma unroll
    for (int st = 128; st >= 4; st >>= 1) {
        if (t < st) red[t] += red[t + st];
        __syncthreads();
    }
    if (t < 4) sh[t] = 1.f / (red[t] + 1e-16f);
    __syncthreads();

    // phase 3: chunked weighted accumulate. trip count is block-uniform -> in-loop barriers safe.
    int head = t >> 6;                    // thread t owns output dim t; wave-uniform head
    int e4 = t >> 2;
    float acc = 0.f;
    for (int c0 = beg; c0 < end; c0 += 64) {
        int cn = end - c0; if (cn > 64) cn = 64;
        __syncthreads();                  // protect wch/sch from previous iteration's readers
        if (e4 < cn) {
            int s = srcs[c0 + e4];
            if (h4 == 0) sch[e4] = s;
            float l = als[s * 4 + h4] + aldh;
            l = (l > 0.f) ? l : 0.2f * l;
            wch[e4][h4] = expf(l - mh[h4]) * sh[h4];
        }
        __syncthreads();
        for (int e = 0; e < cn; ++e) {
            acc = fmaf(wch[e][head], hbuf[sch[e] * 256 + t], acc);  // coalesced 1KB row read
        }
    }
    float val = acc + bias[t];
    if (RELU) val = fmaxf(val, 0.f);
    xout[n * 256 + t] = val;
    if (JKINIT) jk[n * 256 + t] = val;
    else        jk[n * 256 + t] = fmaxf(jk[n * 256 + t], val);
}

// ---------------- gate: per-graph softmax over 16 graphs ----------------
__device__ __forceinline__ unsigned fenc(float f) {
    int i = __float_as_int(f);
    return (i >= 0) ? ((unsigned)i | 0x80000000u) : ~(unsigned)i;
}
__device__ __forceinline__ float fdec(unsigned u) {
    int i = (u & 0x80000000u) ? (int)(u & 0x7fffffffu) : (int)~u;
    return __int_as_float(i);
}

__global__ void gate_init(unsigned* gm, float* gs) {
    int t = threadIdx.x;
    if (t < NGRAPHS) { gm[t] = fenc(-INFINITY); gs[t] = 0.f; }
}

__global__ __launch_bounds__(256) void gate_logits(
    const float* __restrict__ g1, const float* __restrict__ Wg2, const float* __restrict__ bg2,
    const int* __restrict__ batch, float* __restrict__ logit, unsigned* __restrict__ gm)
{
    __shared__ unsigned lmax[NGRAPHS];
    int t = threadIdx.x;
    if (t < NGRAPHS) lmax[t] = fenc(-INFINITY);
    __syncthreads();
    int wid = t >> 6, lane = t & 63;
    int n = blockIdx.x * 4 + wid;
    float v = 0.f;
    if (n < NNODES) v = g1[n * 64 + lane] * Wg2[lane];
    #pragma unroll
    for (int o = 32; o; o >>= 1) v += __shfl_down(v, o);
    if (n < NNODES && lane == 0) {
        float l = v + bg2[0];
        logit[n] = l;
        atomicMax(&lmax[batch[n]], fenc(l));
    }
    __syncthreads();
    if (t < NGRAPHS && lmax[t] != fenc(-INFINITY)) atomicMax(&gm[t], lmax[t]);
}

__global__ __launch_bounds__(256) void gate_expsum(
    const float* __restrict__ logit, const int* __restrict__ batch,
    const unsigned* __restrict__ gm, float* __restrict__ ebuf, float* __restrict__ gs)
{
    __shared__ float sbin[NGRAPHS];
    int t = threadIdx.x;
    if (t < NGRAPHS) sbin[t] = 0.f;
    __syncthreads();
    int n = blockIdx.x * 256 + t;
    if (n < NNODES) {
        int b = batch[n];
        float e = expf(logit[n] - fdec(gm[b]));
        ebuf[n] = e;
        atomicAdd(&sbin[b], e);
    }
    __syncthreads();
    if (t < NGRAPHS && sbin[t] != 0.f) atomicAdd(&gs[t], sbin[t]);
}

__global__ void gate_norm(const float* __restrict__ ebuf, const int* __restrict__ batch,
                          const float* __restrict__ gs, float* __restrict__ gate)
{
    int n = blockIdx.x * 256 + threadIdx.x;
    if (n < NNODES) gate[n] = ebuf[n] / (gs[batch[n]] + 1e-16f);
}

// ---------------- launch ----------------
extern "C" void kernel_launch(void* const* d_in, const int* in_sizes, int n_in,
                              void* d_out, int out_size, void* d_ws, size_t ws_size,
                              hipStream_t stream)
{
    const float* x     = (const float*)d_in[0];
    const int*   ei    = (const int*)  d_in[1];
    const int*   batch = (const int*)  d_in[2];
    const float* W [4] = {(const float*)d_in[3],  (const float*)d_in[7],  (const float*)d_in[11], (const float*)d_in[15]};
    const float* AS[4] = {(const float*)d_in[4],  (const float*)d_in[8],  (const float*)d_in[12], (const float*)d_in[16]};
    const float* AD[4] = {(const float*)d_in[5],  (const float*)d_in[9],  (const float*)d_in[13], (const float*)d_in[17]};
    const float* Bi[4] = {(const float*)d_in[6],  (const float*)d_in[10], (const float*)d_in[14], (const float*)d_in[18]};
    const float* Wg1 = (const float*)d_in[19]; const float* bg1 = (const float*)d_in[20];
    const float* Wg2 = (const float*)d_in[21]; const float* bg2 = (const float*)d_in[22];
    const float* Wm1 = (const float*)d_in[23]; const float* bm1 = (const float*)d_in[24];
    const float* Wm2 = (const float*)d_in[25]; const float* bm2 = (const float*)d_in[26];
    const float* Wm3 = (const float*)d_in[27]; const float* bm3 = (const float*)d_in[28];
    float* out = (float*)d_out;

    char* w = (char*)d_ws;
    size_t o = 0;
    auto alloc = [&](size_t bytes) { char* p = w + o; o += (bytes + 255) & ~(size_t)255; return p; };
    float*    bufA  = (float*)   alloc((size_t)NNODES * 256 * 4);  // x_l / h1
    float*    bufB  = (float*)   alloc((size_t)NNODES * 256 * 4);  // h_l / g1 / h2
    float*    jk    = (float*)   alloc((size_t)NNODES * 256 * 4);
    float*    als   = (float*)   alloc((size_t)NNODES * 4 * 4);
    float*    ald   = (float*)   alloc((size_t)NNODES * 4 * 4);
    float*    logit = (float*)   alloc((size_t)NNODES * 4);
    float*    ebuf  = (float*)   alloc((size_t)NNODES * 4);
    float*    gate  = (float*)   alloc((size_t)NNODES * 4);
    unsigned* gmv   = (unsigned*)alloc(NGRAPHS * 4);
    float*    gsv   = (float*)   alloc(NGRAPHS * 4);
    int*      cnt   = (int*)     alloc((size_t)NNODES * 4);
    int*      cur   = (int*)     alloc((size_t)NNODES * 4);
    int*      off   = (int*)     alloc((size_t)(NNODES + 1) * 4);
    int*      srcs  = (int*)     alloc((size_t)NEDGES * 4);

    hipMemsetAsync(cnt, 0, (size_t)NNODES * 4, stream);
    hipMemsetAsync(cur, 0, (size_t)NNODES * 4, stream);
    gate_init<<<1, 64, 0, stream>>>(gmv, gsv);

    // CSR (dst-grouped) rebuilt every call
    hist_kernel   <<<(NEDGES + 255) / 256, 256, 0, stream>>>(ei, cnt);
    scan_kernel   <<<1, 256, 0, stream>>>(cnt, off);
    scatter_kernel<<<(NEDGES + 255) / 256, 256, 0, stream>>>(ei, off, cur, srcs);

    const int MB = (NNODES + 63) / 64;   // 313

    // layer 0: h = x @ W0  (K=128)
    gemm_kernel<0,0,0><<<dim3(MB, 4), 256, 0, stream>>>(x, 128, nullptr, W[0], nullptr, bufB, NNODES, 256, 128);
    att_logits<<<NNODES, 256, 0, stream>>>(bufB, AS[0], AD[0], als, ald);
    gat_aggregate<1,1><<<NNODES, 256, 0, stream>>>(bufB, als, ald, Bi[0], off, srcs, bufA, jk);

    // layers 1..3 (relu on 1,2; none on 3)
    for (int l = 1; l < 4; ++l) {
        gemm_kernel<0,0,0><<<dim3(MB, 4), 256, 0, stream>>>(bufA, 256, nullptr, W[l], nullptr, bufB, NNODES, 256, 256);
        att_logits<<<NNODES, 256, 0, stream>>>(bufB, AS[l], AD[l], als, ald);
        if (l < 3) gat_aggregate<1,0><<<NNODES, 256, 0, stream>>>(bufB, als, ald, Bi[l], off, srcs, bufA, jk);
        else       gat_aggregate<0,0><<<NNODES, 256, 0, stream>>>(bufB, als, ald, Bi[l], off, srcs, bufA, jk);
    }

    // gate path: g1 = relu(jk @ Wg1 + bg1); logits; per-graph softmax
    gemm_kernel<1,1,0><<<dim3(MB, 1), 256, 0, stream>>>(jk, 256, nullptr, Wg1, bg1, bufB, NNODES, 64, 256);
    gate_logits<<<(NNODES + 3) / 4, 256, 0, stream>>>(bufB, Wg2, bg2, batch, logit, gmv);
    gate_expsum<<<(NNODES + 255) / 256, 256, 0, stream>>>(logit, batch, gmv, ebuf, gsv);
    gate_norm  <<<(NNODES + 255) / 256, 256, 0, stream>>>(ebuf, batch, gsv, gate);

    // MLP head; [jk | gate] concat folded into GEMM as virtual extra column (K=257)
    gemm_kernel<1,1,1><<<dim3(MB, 2), 256, 0, stream>>>(jk,   256, gate,    Wm1, bm1, bufA, NNODES, 128, 257);
    gemm_kernel<1,1,0><<<dim3(MB, 1), 256, 0, stream>>>(bufA, 128, nullptr, Wm2, bm2, bufB, NNODES, 64, 128);
    gemm_kernel<0,1,0><<<dim3(MB, 1), 256, 0, stream>>>(bufB, 64,  nullptr, Wm3, bm3, out,  NNODES, 10, 64);
}

// Round 10
// 731.737 us; speedup vs baseline: 1.2093x; 1.2093x over previous
//
#include <hip/hip_runtime.h>
#include <math.h>

#define NNODES 20000
#define NEDGES 320000
#define NGRAPHS 16

typedef unsigned short ushort_t;
typedef __attribute__((ext_vector_type(8))) short bf16x8;
typedef __attribute__((ext_vector_type(4))) float f32x4;

__device__ __forceinline__ ushort_t f2bf(float f) {  // RNE
    unsigned u = __float_as_uint(f);
    return (ushort_t)((u + 0x7fffu + ((u >> 16) & 1u)) >> 16);
}
__device__ __forceinline__ float bf2f(ushort_t b) {
    return __uint_as_float(((unsigned)b) << 16);
}

// ---------------- bf16 MFMA GEMM: C[M,N] = A[M,K] @ Bt[N,K]^T, all bf16, fp32 accum -------------
// 64x64 tile, 256 thr = 4 waves in 2x2, each wave 32x32 = 2x2 16x16x32 fragments.
// LDS rows padded to 40 shorts (80B = 5*16B): keeps ds_read_b128 alignment, uniform bank spread.
__global__ __launch_bounds__(256) void gemm_mfma(
    const ushort_t* __restrict__ A,   // [M,K] bf16
    const ushort_t* __restrict__ Bt,  // [N,K] bf16 (pre-transposed weights)
    ushort_t* __restrict__ C,         // [M,N] bf16
    int M, int N, int K)
{
    __shared__ short As[64][40];
    __shared__ short Bs[64][40];
    int t = threadIdx.x;
    int lane = t & 63, w = t >> 6;
    int wr = w >> 1, wc = w & 1;
    int row0 = blockIdx.x * 64, col0 = blockIdx.y * 64;

    f32x4 acc[2][2];
    #pragma unroll
    for (int i = 0; i < 2; ++i)
        #pragma unroll
        for (int j = 0; j < 2; ++j) acc[i][j] = (f32x4){0.f, 0.f, 0.f, 0.f};

    int srow = t >> 2, sk8 = (t & 3) * 8;   // staging: thread -> (row/col, 8-elem k chunk)

    for (int k0 = 0; k0 < K; k0 += 32) {
        int gr = row0 + srow;
        bf16x8 av = {};
        if (gr < M) av = *(const bf16x8*)(A + (size_t)gr * K + k0 + sk8);
        *(bf16x8*)&As[srow][sk8] = av;
        *(bf16x8*)&Bs[srow][sk8] = *(const bf16x8*)(Bt + (size_t)(col0 + srow) * K + k0 + sk8);
        __syncthreads();

        int kb = (lane >> 4) * 8;   // A/B frag: outer = lane&15, k = (lane>>4)*8 + j
        int rl = lane & 15;
        bf16x8 af0 = *(const bf16x8*)&As[wr * 32 + rl][kb];
        bf16x8 af1 = *(const bf16x8*)&As[wr * 32 + 16 + rl][kb];
        bf16x8 bf0 = *(const bf16x8*)&Bs[wc * 32 + rl][kb];
        bf16x8 bf1 = *(const bf16x8*)&Bs[wc * 32 + 16 + rl][kb];
        acc[0][0] = __builtin_amdgcn_mfma_f32_16x16x32_bf16(af0, bf0, acc[0][0], 0, 0, 0);
        acc[0][1] = __builtin_amdgcn_mfma_f32_16x16x32_bf16(af0, bf1, acc[0][1], 0, 0, 0);
        acc[1][0] = __builtin_amdgcn_mfma_f32_16x16x32_bf16(af1, bf0, acc[1][0], 0, 0, 0);
        acc[1][1] = __builtin_amdgcn_mfma_f32_16x16x32_bf16(af1, bf1, acc[1][1], 0, 0, 0);
        __syncthreads();
    }
    // C/D layout (m89-verified): col = lane&15, row = (lane>>4)*4 + reg
    #pragma unroll
    for (int fi = 0; fi < 2; ++fi) {
        int rbase = row0 + wr * 32 + fi * 16 + (lane >> 4) * 4;
        #pragma unroll
        for (int fj = 0; fj < 2; ++fj) {
            int col = col0 + wc * 32 + fj * 16 + (lane & 15);
            #pragma unroll
            for (int r = 0; r < 4; ++r) {
                int gr = rbase + r;
                if (gr < M) C[(size_t)gr * N + col] = f2bf(acc[fi][fj][r]);
            }
        }
    }
}

// weight transpose+convert: Wt[n][k] = bf16(W[k][n])
__global__ void cvt_wt(const float* __restrict__ W, ushort_t* __restrict__ Wt, int K, int N) {
    int idx = blockIdx.x * 256 + threadIdx.x;
    if (idx >= K * N) return;
    int n = idx / K, k = idx - n * K;
    Wt[idx] = f2bf(W[(size_t)k * N + n]);
}
__global__ void cvt_xb(const float* __restrict__ x, ushort_t* __restrict__ xb, int total) {
    int idx = blockIdx.x * 256 + threadIdx.x;
    if (idx < total) xb[idx] = f2bf(x[idx]);
}

// ---------------- generic tiled fp32 GEMM (gate/MLP path): C = A@B (+bias, relu) ----------------
template<int RELU, int HASBIAS, int HASEXTRA>
__global__ __launch_bounds__(256) void gemm_kernel(
    const float* __restrict__ A, int Astride,
    const float* __restrict__ extracol,
    const float* __restrict__ B,
    const float* __restrict__ bias,
    float* __restrict__ C,
    int M, int N, int K)
{
    __shared__ float Asf[16][68];
    __shared__ float Bsf[16][64];
    int t  = threadIdx.x;
    int tx = t & 15, ty = t >> 4;
    int row0 = blockIdx.x * 64;
    int col0 = blockIdx.y * 64;
    float acc[4][4] = {};
    for (int k0 = 0; k0 < K; k0 += 16) {
        #pragma unroll
        for (int i = 0; i < 4; ++i) {
            int idx = t + i * 256;
            int m = idx >> 4, kk = idx & 15;
            int gr = row0 + m, gk = k0 + kk;
            float v = 0.f;
            if (gr < M && gk < K) {
                if (HASEXTRA && gk == K - 1) v = extracol[gr];
                else                         v = A[gr * Astride + gk];
            }
            Asf[kk][m] = v;
        }
        #pragma unroll
        for (int i = 0; i < 4; ++i) {
            int idx = t + i * 256;
            int kk = idx >> 6, nn = idx & 63;
            int gk = k0 + kk, gn = col0 + nn;
            Bsf[kk][nn] = (gk < K && gn < N) ? B[gk * N + gn] : 0.f;
        }
        __syncthreads();
        #pragma unroll
        for (int kk = 0; kk < 16; ++kk) {
            float a[4], b[4];
            #pragma unroll
            for (int i = 0; i < 4; ++i) a[i] = Asf[kk][ty * 4 + i];
            #pragma unroll
            for (int j = 0; j < 4; ++j) b[j] = Bsf[kk][tx * 4 + j];
            #pragma unroll
            for (int i = 0; i < 4; ++i)
                #pragma unroll
                for (int j = 0; j < 4; ++j)
                    acc[i][j] = fmaf(a[i], b[j], acc[i][j]);
        }
        __syncthreads();
    }
    #pragma unroll
    for (int i = 0; i < 4; ++i) {
        int gr = row0 + ty * 4 + i;
        if (gr >= M) continue;
        #pragma unroll
        for (int j = 0; j < 4; ++j) {
            int gn = col0 + tx * 4 + j;
            if (gn >= N) continue;
            float v = acc[i][j];
            if (HASBIAS) v += bias[gn];
            if (RELU)    v = fmaxf(v, 0.f);
            C[gr * N + gn] = v;
        }
    }
}

// ---------------- per-node attention logits from bf16 h ----------------
__global__ __launch_bounds__(256) void att_logits(
    const ushort_t* __restrict__ h, const float* __restrict__ a_s, const float* __restrict__ a_d,
    float* __restrict__ als, float* __restrict__ ald)
{
    int n = blockIdx.x, t = threadIdx.x;      // wave w == head w
    float v  = bf2f(h[n * 256 + t]);
    float ps = v * a_s[t];
    float pd = v * a_d[t];
    #pragma unroll
    for (int o = 32; o; o >>= 1) { ps += __shfl_down(ps, o); pd += __shfl_down(pd, o); }
    if ((t & 63) == 0) {
        int head = t >> 6;
        als[n * 4 + head] = ps;
        ald[n * 4 + head] = pd;
    }
}

// ---------------- CSR build (dst-grouped) ----------------
__global__ void hist_kernel(const int* __restrict__ ei, int* __restrict__ cnt) {
    int e = blockIdx.x * 256 + threadIdx.x;
    if (e < NEDGES) atomicAdd(&cnt[ei[NEDGES + e]], 1);
}

__global__ void scan_kernel(const int* __restrict__ cnt, int* __restrict__ off) {
    const int P = (NNODES + 255) / 256;   // 79
    int t = threadIdx.x;
    int lo = t * P, hi = lo + P; if (hi > NNODES) hi = NNODES; if (lo > NNODES) lo = NNODES;
    int s = 0;
    for (int i = lo; i < hi; ++i) s += cnt[i];
    int lane = t & 63, wv = t >> 6;
    int v = s;
    #pragma unroll
    for (int o = 1; o < 64; o <<= 1) {
        int u = __shfl_up(v, o);
        if (lane >= o) v += u;
    }
    __shared__ int ws[4];
    if (lane == 63) ws[wv] = v;
    __syncthreads();
    int wbase = 0;
    for (int i = 0; i < wv; ++i) wbase += ws[i];
    int run = wbase + v - s;
    for (int i = lo; i < hi; ++i) { off[i] = run; run += cnt[i]; }
    if (t == 255) off[NNODES] = run;
}

__global__ void scatter_kernel(const int* __restrict__ ei, const int* __restrict__ off,
                               int* __restrict__ cur, int* __restrict__ srcs) {
    int e = blockIdx.x * 256 + threadIdx.x;
    if (e < NEDGES) {
        int d = ei[NEDGES + e];
        int pos = off[d] + atomicAdd(&cur[d], 1);
        srcs[pos] = ei[e];
    }
}

// ---------------- GAT aggregation: bf16 h gather, fp32 softmax/accum ----------------
template<int RELU, int JKINIT>
__global__ __launch_bounds__(256) void gat_aggregate(
    const ushort_t* __restrict__ hbuf,
    const float* __restrict__ als, const float* __restrict__ ald,
    const float* __restrict__ bias,
    const int* __restrict__ off, const int* __restrict__ srcs,
    ushort_t* __restrict__ xout, float* __restrict__ jk)
{
    int n = blockIdx.x, t = threadIdx.x;
    int beg = off[n], end = off[n + 1];
    __shared__ float red[256];
    __shared__ float mh[4], sh[4];
    __shared__ float wch[64][4];
    __shared__ int   sch[64];

    int h4 = t & 3;
    float aldh = ald[n * 4 + h4];
    float lmax = -INFINITY;
    for (int e = beg + (t >> 2); e < end; e += 64) {
        int s = srcs[e];
        float l = als[s * 4 + h4] + aldh;
        l = (l > 0.f) ? l : 0.2f * l;
        lmax = fmaxf(lmax, l);
    }
    red[t] = lmax;
    __syncthreads();
    #pragma unroll
    for (int st = 128; st >= 4; st >>= 1) {
        if (t < st) red[t] = fmaxf(red[t], red[t + st]);
        __syncthreads();
    }
    if (t < 4) { float m = red[t]; mh[t] = (m == -INFINITY) ? 0.f : m; }
    __syncthreads();

    float mhh = mh[h4];
    float lsum = 0.f;
    for (int e = beg + (t >> 2); e < end; e += 64) {
        int s = srcs[e];
        float l = als[s * 4 + h4] + aldh;
        l = (l > 0.f) ? l : 0.2f * l;
        lsum += expf(l - mhh);
    }
    red[t] = lsum;
    __syncthreads();
    #pragma unroll
    for (int st = 128; st >= 4; st >>= 1) {
        if (t < st) red[t] += red[t + st];
        __syncthreads();
    }
    if (t < 4) sh[t] = 1.f / (red[t] + 1e-16f);
    __syncthreads();

    int head = t >> 6;
    int e4 = t >> 2;
    float acc = 0.f;
    for (int c0 = beg; c0 < end; c0 += 64) {
        int cn = end - c0; if (cn > 64) cn = 64;
        __syncthreads();
        if (e4 < cn) {
            int s = srcs[c0 + e4];
            if (h4 == 0) sch[e4] = s;
            float l = als[s * 4 + h4] + aldh;
            l = (l > 0.f) ? l : 0.2f * l;
            wch[e4][h4] = expf(l - mh[h4]) * sh[h4];
        }
        __syncthreads();
        for (int e = 0; e < cn; ++e) {
            acc = fmaf(wch[e][head], bf2f(hbuf[sch[e] * 256 + t]), acc);  // 512B/row bf16 gather
        }
    }
    float val = acc + bias[t];
    if (RELU) val = fmaxf(val, 0.f);
    xout[n * 256 + t] = f2bf(val);          // bf16 x for next layer's MFMA A
    if (JKINIT) jk[n * 256 + t] = val;      // jk stays fp32 for gate/MLP path
    else        jk[n * 256 + t] = fmaxf(jk[n * 256 + t], val);
}

// ---------------- gate: per-graph softmax over 16 graphs ----------------
__device__ __forceinline__ unsigned fenc(float f) {
    int i = __float_as_int(f);
    return (i >= 0) ? ((unsigned)i | 0x80000000u) : ~(unsigned)i;
}
__device__ __forceinline__ float fdec(unsigned u) {
    int i = (u & 0x80000000u) ? (int)(u & 0x7fffffffu) : (int)~u;
    return __int_as_float(i);
}

__global__ void gate_init(unsigned* gm, float* gs) {
    int t = threadIdx.x;
    if (t < NGRAPHS) { gm[t] = fenc(-INFINITY); gs[t] = 0.f; }
}

__global__ __launch_bounds__(256) void gate_logits(
    const float* __restrict__ g1, const float* __restrict__ Wg2, const float* __restrict__ bg2,
    const int* __restrict__ batch, float* __restrict__ logit, unsigned* __restrict__ gm)
{
    __shared__ unsigned lmax[NGRAPHS];
    int t = threadIdx.x;
    if (t < NGRAPHS) lmax[t] = fenc(-INFINITY);
    __syncthreads();
    int wid = t >> 6, lane = t & 63;
    int n = blockIdx.x * 4 + wid;
    float v = 0.f;
    if (n < NNODES) v = g1[n * 64 + lane] * Wg2[lane];
    #pragma unroll
    for (int o = 32; o; o >>= 1) v += __shfl_down(v, o);
    if (n < NNODES && lane == 0) {
        float l = v + bg2[0];
        logit[n] = l;
        atomicMax(&lmax[batch[n]], fenc(l));
    }
    __syncthreads();
    if (t < NGRAPHS && lmax[t] != fenc(-INFINITY)) atomicMax(&gm[t], lmax[t]);
}

__global__ __launch_bounds__(256) void gate_expsum(
    const float* __restrict__ logit, const int* __restrict__ batch,
    const unsigned* __restrict__ gm, float* __restrict__ ebuf, float* __restrict__ gs)
{
    __shared__ float sbin[NGRAPHS];
    int t = threadIdx.x;
    if (t < NGRAPHS) sbin[t] = 0.f;
    __syncthreads();
    int n = blockIdx.x * 256 + t;
    if (n < NNODES) {
        int b = batch[n];
        float e = expf(logit[n] - fdec(gm[b]));
        ebuf[n] = e;
        atomicAdd(&sbin[b], e);
    }
    __syncthreads();
    if (t < NGRAPHS && sbin[t] != 0.f) atomicAdd(&gs[t], sbin[t]);
}

__global__ void gate_norm(const float* __restrict__ ebuf, const int* __restrict__ batch,
                          const float* __restrict__ gs, float* __restrict__ gate)
{
    int n = blockIdx.x * 256 + threadIdx.x;
    if (n < NNODES) gate[n] = ebuf[n] / (gs[batch[n]] + 1e-16f);
}

// ---------------- launch ----------------
extern "C" void kernel_launch(void* const* d_in, const int* in_sizes, int n_in,
                              void* d_out, int out_size, void* d_ws, size_t ws_size,
                              hipStream_t stream)
{
    const float* x     = (const float*)d_in[0];
    const int*   ei    = (const int*)  d_in[1];
    const int*   batch = (const int*)  d_in[2];
    const float* W [4] = {(const float*)d_in[3],  (const float*)d_in[7],  (const float*)d_in[11], (const float*)d_in[15]};
    const float* AS[4] = {(const float*)d_in[4],  (const float*)d_in[8],  (const float*)d_in[12], (const float*)d_in[16]};
    const float* AD[4] = {(const float*)d_in[5],  (const float*)d_in[9],  (const float*)d_in[13], (const float*)d_in[17]};
    const float* Bi[4] = {(const float*)d_in[6],  (const float*)d_in[10], (const float*)d_in[14], (const float*)d_in[18]};
    const float* Wg1 = (const float*)d_in[19]; const float* bg1 = (const float*)d_in[20];
    const float* Wg2 = (const float*)d_in[21]; const float* bg2 = (const float*)d_in[22];
    const float* Wm1 = (const float*)d_in[23]; const float* bm1 = (const float*)d_in[24];
    const float* Wm2 = (const float*)d_in[25]; const float* bm2 = (const float*)d_in[26];
    const float* Wm3 = (const float*)d_in[27]; const float* bm3 = (const float*)d_in[28];
    float* out = (float*)d_out;

    char* w = (char*)d_ws;
    size_t o = 0;
    auto alloc = [&](size_t bytes) { char* p = w + o; o += (bytes + 255) & ~(size_t)255; return p; };
    ushort_t* xA    = (ushort_t*)alloc((size_t)NNODES * 256 * 2);  // bf16 x_l (hosts xb at L0)
    ushort_t* hB    = (ushort_t*)alloc((size_t)NNODES * 256 * 2);  // bf16 h_l
    float*    jk    = (float*)   alloc((size_t)NNODES * 256 * 4);  // fp32 JK-max
    ushort_t* Wt[4];
    Wt[0] = (ushort_t*)alloc((size_t)128 * 256 * 2);
    for (int l = 1; l < 4; ++l) Wt[l] = (ushort_t*)alloc((size_t)256 * 256 * 2);
    float*    bufF1 = (float*)   alloc((size_t)NNODES * 64 * 4);   // g1 / m2
    float*    bufF2 = (float*)   alloc((size_t)NNODES * 128 * 4);  // m1
    float*    als   = (float*)   alloc((size_t)NNODES * 4 * 4);
    float*    ald   = (float*)   alloc((size_t)NNODES * 4 * 4);
    float*    logit = (float*)   alloc((size_t)NNODES * 4);
    float*    ebuf  = (float*)   alloc((size_t)NNODES * 4);
    float*    gate  = (float*)   alloc((size_t)NNODES * 4);
    unsigned* gmv   = (unsigned*)alloc(NGRAPHS * 4);
    float*    gsv   = (float*)   alloc(NGRAPHS * 4);
    int*      cnt   = (int*)     alloc((size_t)NNODES * 4);
    int*      cur   = (int*)     alloc((size_t)NNODES * 4);
    int*      off   = (int*)     alloc((size_t)(NNODES + 1) * 4);
    int*      srcs  = (int*)     alloc((size_t)NEDGES * 4);

    hipMemsetAsync(cnt, 0, (size_t)NNODES * 4, stream);
    hipMemsetAsync(cur, 0, (size_t)NNODES * 4, stream);
    gate_init<<<1, 64, 0, stream>>>(gmv, gsv);

    // weight transpose+convert, x convert (xb shares xA buffer; dead after L0 GEMM)
    cvt_wt<<<(128 * 256 + 255) / 256, 256, 0, stream>>>(W[0], Wt[0], 128, 256);
    for (int l = 1; l < 4; ++l)
        cvt_wt<<<(256 * 256 + 255) / 256, 256, 0, stream>>>(W[l], Wt[l], 256, 256);
    cvt_xb<<<(NNODES * 128 + 255) / 256, 256, 0, stream>>>(x, xA, NNODES * 128);

    // CSR (dst-grouped) rebuilt every call
    hist_kernel   <<<(NEDGES + 255) / 256, 256, 0, stream>>>(ei, cnt);
    scan_kernel   <<<1, 256, 0, stream>>>(cnt, off);
    scatter_kernel<<<(NEDGES + 255) / 256, 256, 0, stream>>>(ei, off, cur, srcs);

    const int MB = (NNODES + 63) / 64;   // 313

    // layer 0 (K=128): h = xb @ W0
    gemm_mfma<<<dim3(MB, 4), 256, 0, stream>>>(xA, Wt[0], hB, NNODES, 256, 128);
    att_logits<<<NNODES, 256, 0, stream>>>(hB, AS[0], AD[0], als, ald);
    gat_aggregate<1,1><<<NNODES, 256, 0, stream>>>(hB, als, ald, Bi[0], off, srcs, xA, jk);

    // layers 1..3 (relu on 1,2; none on 3)
    for (int l = 1; l < 4; ++l) {
        gemm_mfma<<<dim3(MB, 4), 256, 0, stream>>>(xA, Wt[l], hB, NNODES, 256, 256);
        att_logits<<<NNODES, 256, 0, stream>>>(hB, AS[l], AD[l], als, ald);
        if (l < 3) gat_aggregate<1,0><<<NNODES, 256, 0, stream>>>(hB, als, ald, Bi[l], off, srcs, xA, jk);
        else       gat_aggregate<0,0><<<NNODES, 256, 0, stream>>>(hB, als, ald, Bi[l], off, srcs, xA, jk);
    }

    // gate path (fp32): g1 = relu(jk @ Wg1 + bg1); per-graph softmax
    gemm_kernel<1,1,0><<<dim3(MB, 1), 256, 0, stream>>>(jk, 256, nullptr, Wg1, bg1, bufF1, NNODES, 64, 256);
    gate_logits<<<(NNODES + 3) / 4, 256, 0, stream>>>(bufF1, Wg2, bg2, batch, logit, gmv);
    gate_expsum<<<(NNODES + 255) / 256, 256, 0, stream>>>(logit, batch, gmv, ebuf, gsv);
    gate_norm  <<<(NNODES + 255) / 256, 256, 0, stream>>>(ebuf, batch, gsv, gate);

    // MLP head (fp32); [jk | gate] folded via virtual K=257 column
    gemm_kernel<1,1,1><<<dim3(MB, 2), 256, 0, stream>>>(jk,    256, gate,    Wm1, bm1, bufF2, NNODES, 128, 257);
    gemm_kernel<1,1,0><<<dim3(MB, 1), 256, 0, stream>>>(bufF2, 128, nullptr, Wm2, bm2, bufF1, NNODES, 64, 128);
    gemm_kernel<0,1,0><<<dim3(MB, 1), 256, 0, stream>>>(bufF1, 64,  nullptr, Wm3, bm3, out,   NNODES, 10, 64);
}